// Round 1
// baseline (12443.461 us; speedup 1.0000x reference)
//
#include <hip/hip_runtime.h>
#include <cstdint>
#include <cstddef>

#define BATCH 128
#define INF   64
#define OUTF  16
#define SEQ   512
#define FUT   96
#define HID   512
#define G4    2048   // 4*HID
#define PROJ  48

__device__ __forceinline__ float fsigmoid(float x) {
    float e = __builtin_amdgcn_exp2f(-1.4426950408889634f * x);
    return __builtin_amdgcn_rcpf(1.0f + e);
}
__device__ __forceinline__ float ftanh(float x) {
    // tanh(x) = 1 - 2/(exp(2x)+1), exp(2x) = exp2(x*2*log2(e))
    float e = __builtin_amdgcn_exp2f(2.8853900817779268f * x);
    return 1.0f - 2.0f * __builtin_amdgcn_rcpf(1.0f + e);
}

// ---------------- init: zero states, build first_prev ----------------
__global__ void k_init(const float* __restrict__ x, float* __restrict__ hs,
                       float* __restrict__ cs, float* __restrict__ prev) {
    int idx = blockIdx.x * 256 + threadIdx.x;            // grid 512*256 = 131072
    if (idx < 2 * BATCH * PROJ) hs[idx] = 0.f;
    if (idx < 2 * BATCH * HID)  cs[idx] = 0.f;
    if (idx < BATCH * PROJ) {
        int b = idx / PROJ, p = idx % PROJ;
        prev[idx] = x[(size_t)b * INF * SEQ + (size_t)p * SEQ + (SEQ - 1)];
    }
}

// ---------------- transpose x[b][k][t] -> xT[(t*B+b)*INF + k] ----------------
__global__ void k_transpose(const float* __restrict__ x, float* __restrict__ xT) {
    __shared__ float tile[32][33];
    int b  = blockIdx.z;
    int t0 = blockIdx.x * 32;
    int k0 = blockIdx.y * 32;
    int tx = threadIdx.x, ty = threadIdx.y; // 32 x 8
    #pragma unroll
    for (int i = 0; i < 4; ++i) {
        int k = k0 + ty + 8 * i;
        tile[ty + 8 * i][tx] = x[(size_t)b * INF * SEQ + (size_t)k * SEQ + t0 + tx];
    }
    __syncthreads();
    #pragma unroll
    for (int i = 0; i < 4; ++i) {
        int t = t0 + ty + 8 * i;
        xT[((size_t)t * BATCH + b) * INF + k0 + tx] = tile[tx][ty + 8 * i];
    }
}

// ---------------- input-gates GEMM: G[row][g] = A[row]·W[g] + bih[g]+bhh[g] ----------------
// rows are chunk-local (row0 applied to A); BM=BN=128, BK=16; block 256 threads.
__global__ __launch_bounds__(256) void k_gates(
    const float* __restrict__ A, int K, int row0,
    const float* __restrict__ W, const float* __restrict__ bih,
    const float* __restrict__ bhh, float* __restrict__ G)
{
    __shared__ float Ast[16][132];
    __shared__ float Wst[16][132];
    int rb = blockIdx.x * 128;
    int cb = blockIdx.y * 128;
    int tid = threadIdx.x;
    int rg = tid & 15;   // row group: rows rg*8 .. rg*8+7
    int cg = tid >> 4;   // col group: cols cg*8 .. cg*8+7
    float acc[8][8];
    #pragma unroll
    for (int j = 0; j < 8; ++j)
        #pragma unroll
        for (int i = 0; i < 8; ++i) acc[j][i] = 0.f;

    int nk = K / 16;
    for (int ko = 0; ko < nk; ++ko) {
        #pragma unroll
        for (int l = 0; l < 8; ++l) {
            int idx = tid + l * 256;
            int r = idx >> 4, k = idx & 15;
            Ast[k][r] = A[(size_t)(row0 + rb + r) * K + ko * 16 + k];
            Wst[k][r] = W[(size_t)(cb + r) * K + ko * 16 + k];
        }
        __syncthreads();
        #pragma unroll
        for (int k = 0; k < 16; ++k) {
            float4 a0 = *reinterpret_cast<const float4*>(&Ast[k][rg * 8]);
            float4 a1 = *reinterpret_cast<const float4*>(&Ast[k][rg * 8 + 4]);
            float4 w0 = *reinterpret_cast<const float4*>(&Wst[k][cg * 8]);
            float4 w1 = *reinterpret_cast<const float4*>(&Wst[k][cg * 8 + 4]);
            float av[8] = {a0.x, a0.y, a0.z, a0.w, a1.x, a1.y, a1.z, a1.w};
            float wv[8] = {w0.x, w0.y, w0.z, w0.w, w1.x, w1.y, w1.z, w1.w};
            #pragma unroll
            for (int j = 0; j < 8; ++j)
                #pragma unroll
                for (int i = 0; i < 8; ++i) acc[j][i] += av[j] * wv[i];
        }
        __syncthreads();
    }
    int c0 = cb + cg * 8;
    float bsum[8];
    #pragma unroll
    for (int i = 0; i < 8; ++i) bsum[i] = bih[c0 + i] + bhh[c0 + i];
    #pragma unroll
    for (int j = 0; j < 8; ++j) {
        int r = rb + rg * 8 + j;
        float4 o0, o1;
        o0.x = acc[j][0] + bsum[0]; o0.y = acc[j][1] + bsum[1];
        o0.z = acc[j][2] + bsum[2]; o0.w = acc[j][3] + bsum[3];
        o1.x = acc[j][4] + bsum[4]; o1.y = acc[j][5] + bsum[5];
        o1.z = acc[j][6] + bsum[6]; o1.w = acc[j][7] + bsum[7];
        *reinterpret_cast<float4*>(&G[(size_t)r * G4 + c0])     = o0;
        *reinterpret_cast<float4*>(&G[(size_t)r * G4 + c0 + 4]) = o1;
    }
}

// ---------------- recurrent phase: one WG per batch element ----------------
// thread j owns hidden unit j (gate rows j, j+512, j+1024, j+1536).
__global__ __launch_bounds__(512) void k_rnn(
    const float* __restrict__ G,      // [nt*BATCH][G4] chunk-local
    const float* __restrict__ Whh,    // [G4][PROJ]
    const float* __restrict__ Whr,    // [PROJ][HID]
    float* __restrict__ Hout,         // [SEQ][BATCH][PROJ]
    float* __restrict__ h_state,      // [BATCH][PROJ]
    float* __restrict__ c_state,      // [BATCH][HID]
    int t0, int nt)
{
    __shared__ float whr_lo[PROJ][256];            // j in [0,256)
    __shared__ __align__(16) float ht_lds[HID];
    __shared__ __align__(16) float h_cur[PROJ];
    int b = blockIdx.x;
    int j = threadIdx.x;
    int wave = j >> 6, lane = j & 63;

    // Whh rows -> 192 VGPRs
    float wI[PROJ], wF[PROJ], wG[PROJ], wO[PROJ];
    #pragma unroll
    for (int k4 = 0; k4 < 12; ++k4) {
        float4 vi = *reinterpret_cast<const float4*>(&Whh[(size_t)j * PROJ + 4 * k4]);
        float4 vf = *reinterpret_cast<const float4*>(&Whh[(size_t)(j + HID) * PROJ + 4 * k4]);
        float4 vg = *reinterpret_cast<const float4*>(&Whh[(size_t)(j + 2 * HID) * PROJ + 4 * k4]);
        float4 vo = *reinterpret_cast<const float4*>(&Whh[(size_t)(j + 3 * HID) * PROJ + 4 * k4]);
        wI[4*k4+0]=vi.x; wI[4*k4+1]=vi.y; wI[4*k4+2]=vi.z; wI[4*k4+3]=vi.w;
        wF[4*k4+0]=vf.x; wF[4*k4+1]=vf.y; wF[4*k4+2]=vf.z; wF[4*k4+3]=vf.w;
        wG[4*k4+0]=vg.x; wG[4*k4+1]=vg.y; wG[4*k4+2]=vg.z; wG[4*k4+3]=vg.w;
        wO[4*k4+0]=vo.x; wO[4*k4+1]=vo.y; wO[4*k4+2]=vo.z; wO[4*k4+3]=vo.w;
    }
    // Whr low half -> LDS
    for (int idx = j; idx < PROJ * 256; idx += 512) {
        int p = idx >> 8, jj = idx & 255;
        whr_lo[p][jj] = Whr[(size_t)p * HID + jj];
    }
    // Whr high half -> per-wave registers (wave w owns outputs 6w..6w+5)
    float wr[6][4];
    #pragma unroll
    for (int q = 0; q < 6; ++q)
        #pragma unroll
        for (int m = 0; m < 4; ++m)
            wr[q][m] = Whr[(size_t)(wave * 6 + q) * HID + 256 + lane + 64 * m];

    float c = c_state[(size_t)b * HID + j];
    if (j < PROJ) h_cur[j] = h_state[(size_t)b * PROJ + j];
    __syncthreads();

    // prefetch G for step 0
    const float* Gr = G + (size_t)b * G4;
    float gi = Gr[j], gf = Gr[j + HID], gg = Gr[j + 2 * HID], go = Gr[j + 3 * HID];

    for (int ct = 0; ct < nt; ++ct) {
        float ai = gi, af = gf, ag = gg, ao = go;
        #pragma unroll
        for (int k4 = 0; k4 < 12; ++k4) {
            float4 h4 = *reinterpret_cast<const float4*>(&h_cur[4 * k4]);
            ai += wI[4*k4+0]*h4.x + wI[4*k4+1]*h4.y + wI[4*k4+2]*h4.z + wI[4*k4+3]*h4.w;
            af += wF[4*k4+0]*h4.x + wF[4*k4+1]*h4.y + wF[4*k4+2]*h4.z + wF[4*k4+3]*h4.w;
            ag += wG[4*k4+0]*h4.x + wG[4*k4+1]*h4.y + wG[4*k4+2]*h4.z + wG[4*k4+3]*h4.w;
            ao += wO[4*k4+0]*h4.x + wO[4*k4+1]*h4.y + wO[4*k4+2]*h4.z + wO[4*k4+3]*h4.w;
        }
        if (ct + 1 < nt) {
            const float* Gn = G + ((size_t)(ct + 1) * BATCH + b) * G4;
            gi = Gn[j]; gf = Gn[j + HID]; gg = Gn[j + 2 * HID]; go = Gn[j + 3 * HID];
        }
        float si = fsigmoid(ai), sf = fsigmoid(af), so = fsigmoid(ao), tg = ftanh(ag);
        c = sf * c + si * tg;
        ht_lds[j] = so * ftanh(c);
        __syncthreads();
        // projection h = Whr . ht  (wave w -> outputs 6w..6w+5)
        float rq[6];
        #pragma unroll
        for (int q = 0; q < 6; ++q) {
            int p = wave * 6 + q;
            float s = 0.f;
            #pragma unroll
            for (int m = 0; m < 4; ++m) s += whr_lo[p][lane + 64 * m] * ht_lds[lane + 64 * m];
            #pragma unroll
            for (int m = 0; m < 4; ++m) s += wr[q][m] * ht_lds[256 + lane + 64 * m];
            #pragma unroll
            for (int o = 32; o; o >>= 1) s += __shfl_xor(s, o, 64);
            rq[q] = s;
        }
        if (lane == 0) {
            int t = t0 + ct;
            #pragma unroll
            for (int q = 0; q < 6; ++q) {
                h_cur[wave * 6 + q] = rq[q];
                Hout[((size_t)t * BATCH + b) * PROJ + wave * 6 + q] = rq[q];
            }
        }
        __syncthreads();
    }
    c_state[(size_t)b * HID + j] = c;
    if (j < PROJ) h_state[(size_t)b * PROJ + j] = h_cur[j];
}

// ---------------- decoder: 64 WGs x 2 batches, weights streamed from L2 ----------------
__global__ __launch_bounds__(512) void k_dec(
    const float* __restrict__ xdec,
    const float* __restrict__ Wih0, const float* __restrict__ Whh0,
    const float* __restrict__ bih0, const float* __restrict__ bhh0,
    const float* __restrict__ Whr0,
    const float* __restrict__ Wih1, const float* __restrict__ Whh1,
    const float* __restrict__ bih1, const float* __restrict__ bhh1,
    const float* __restrict__ Whr1,
    const float* __restrict__ h_state, const float* __restrict__ c_state,
    const float* __restrict__ prev_init, float* __restrict__ PRED)
{
    __shared__ __align__(16) float inp0[2][64];
    __shared__ __align__(16) float h0[2][PROJ];
    __shared__ __align__(16) float h1[2][PROJ];
    __shared__ __align__(16) float prev[2][PROJ];
    __shared__ __align__(16) float ht[2][HID];
    int b0 = blockIdx.x * 2;
    int j = threadIdx.x;
    int wave = j >> 6, lane = j & 63;

    float c0[2], c1[2];
    #pragma unroll
    for (int bb = 0; bb < 2; ++bb) {
        c0[bb] = c_state[((size_t)0 * BATCH + b0 + bb) * HID + j];
        c1[bb] = c_state[((size_t)1 * BATCH + b0 + bb) * HID + j];
    }
    if (j < 2 * PROJ) {
        int bb = j / PROJ, p = j % PROJ;
        h0[bb][p]   = h_state[((size_t)0 * BATCH + b0 + bb) * PROJ + p];
        h1[bb][p]   = h_state[((size_t)1 * BATCH + b0 + bb) * PROJ + p];
        prev[bb][p] = prev_init[(size_t)(b0 + bb) * PROJ + p];
    }
    float bI0 = bih0[j] + bhh0[j], bF0 = bih0[j+HID] + bhh0[j+HID];
    float bG0 = bih0[j+2*HID] + bhh0[j+2*HID], bO0 = bih0[j+3*HID] + bhh0[j+3*HID];
    float bI1 = bih1[j] + bhh1[j], bF1 = bih1[j+HID] + bhh1[j+HID];
    float bG1 = bih1[j+2*HID] + bhh1[j+2*HID], bO1 = bih1[j+3*HID] + bhh1[j+3*HID];
    __syncthreads();

    for (int t = 0; t < FUT; ++t) {
        // stage inp0 = [prev, x_t]
        if (j < 2 * PROJ) { int bb = j / PROJ, p = j % PROJ; inp0[bb][p] = prev[bb][p]; }
        else if (j < 2 * PROJ + 2 * OUTF) {
            int idx = j - 2 * PROJ; int bb = idx >> 4, f = idx & 15;
            inp0[bb][PROJ + f] = xdec[(size_t)(b0 + bb) * OUTF * FUT + (size_t)f * FUT + t];
        }
        __syncthreads();
        // ---- layer 0 gates ----
        float aI[2] = {bI0, bI0}, aF[2] = {bF0, bF0}, aG[2] = {bG0, bG0}, aO[2] = {bO0, bO0};
        #pragma unroll
        for (int k4 = 0; k4 < 16; ++k4) {
            float4 wi = *reinterpret_cast<const float4*>(&Wih0[(size_t)j * INF + 4 * k4]);
            float4 wf = *reinterpret_cast<const float4*>(&Wih0[(size_t)(j + HID) * INF + 4 * k4]);
            float4 wg = *reinterpret_cast<const float4*>(&Wih0[(size_t)(j + 2 * HID) * INF + 4 * k4]);
            float4 wo = *reinterpret_cast<const float4*>(&Wih0[(size_t)(j + 3 * HID) * INF + 4 * k4]);
            #pragma unroll
            for (int bb = 0; bb < 2; ++bb) {
                float4 xv = *reinterpret_cast<const float4*>(&inp0[bb][4 * k4]);
                aI[bb] += wi.x*xv.x + wi.y*xv.y + wi.z*xv.z + wi.w*xv.w;
                aF[bb] += wf.x*xv.x + wf.y*xv.y + wf.z*xv.z + wf.w*xv.w;
                aG[bb] += wg.x*xv.x + wg.y*xv.y + wg.z*xv.z + wg.w*xv.w;
                aO[bb] += wo.x*xv.x + wo.y*xv.y + wo.z*xv.z + wo.w*xv.w;
            }
        }
        #pragma unroll
        for (int k4 = 0; k4 < 12; ++k4) {
            float4 wi = *reinterpret_cast<const float4*>(&Whh0[(size_t)j * PROJ + 4 * k4]);
            float4 wf = *reinterpret_cast<const float4*>(&Whh0[(size_t)(j + HID) * PROJ + 4 * k4]);
            float4 wg = *reinterpret_cast<const float4*>(&Whh0[(size_t)(j + 2 * HID) * PROJ + 4 * k4]);
            float4 wo = *reinterpret_cast<const float4*>(&Whh0[(size_t)(j + 3 * HID) * PROJ + 4 * k4]);
            #pragma unroll
            for (int bb = 0; bb < 2; ++bb) {
                float4 xv = *reinterpret_cast<const float4*>(&h0[bb][4 * k4]);
                aI[bb] += wi.x*xv.x + wi.y*xv.y + wi.z*xv.z + wi.w*xv.w;
                aF[bb] += wf.x*xv.x + wf.y*xv.y + wf.z*xv.z + wf.w*xv.w;
                aG[bb] += wg.x*xv.x + wg.y*xv.y + wg.z*xv.z + wg.w*xv.w;
                aO[bb] += wo.x*xv.x + wo.y*xv.y + wo.z*xv.z + wo.w*xv.w;
            }
        }
        #pragma unroll
        for (int bb = 0; bb < 2; ++bb) {
            float si = fsigmoid(aI[bb]), sf = fsigmoid(aF[bb]), so = fsigmoid(aO[bb]);
            float tg = ftanh(aG[bb]);
            c0[bb] = sf * c0[bb] + si * tg;
            ht[bb][j] = so * ftanh(c0[bb]);
        }
        __syncthreads();
        // ---- proj 0 ----
        {
            float r0[6], r1[6];
            #pragma unroll
            for (int q = 0; q < 6; ++q) {
                int p = wave * 6 + q;
                float s0 = 0.f, s1 = 0.f;
                #pragma unroll
                for (int m = 0; m < 8; ++m) {
                    float wv = Whr0[(size_t)p * HID + lane + 64 * m];
                    s0 += wv * ht[0][lane + 64 * m];
                    s1 += wv * ht[1][lane + 64 * m];
                }
                #pragma unroll
                for (int o = 32; o; o >>= 1) { s0 += __shfl_xor(s0, o, 64); s1 += __shfl_xor(s1, o, 64); }
                r0[q] = s0; r1[q] = s1;
            }
            if (lane == 0) {
                #pragma unroll
                for (int q = 0; q < 6; ++q) { h0[0][wave*6+q] = r0[q]; h0[1][wave*6+q] = r1[q]; }
            }
        }
        __syncthreads();
        // ---- layer 1 gates ----
        float dI[2] = {bI1, bI1}, dF[2] = {bF1, bF1}, dG[2] = {bG1, bG1}, dO[2] = {bO1, bO1};
        #pragma unroll
        for (int k4 = 0; k4 < 12; ++k4) {
            float4 wi = *reinterpret_cast<const float4*>(&Wih1[(size_t)j * PROJ + 4 * k4]);
            float4 wf = *reinterpret_cast<const float4*>(&Wih1[(size_t)(j + HID) * PROJ + 4 * k4]);
            float4 wg = *reinterpret_cast<const float4*>(&Wih1[(size_t)(j + 2 * HID) * PROJ + 4 * k4]);
            float4 wo = *reinterpret_cast<const float4*>(&Wih1[(size_t)(j + 3 * HID) * PROJ + 4 * k4]);
            #pragma unroll
            for (int bb = 0; bb < 2; ++bb) {
                float4 xv = *reinterpret_cast<const float4*>(&h0[bb][4 * k4]);
                dI[bb] += wi.x*xv.x + wi.y*xv.y + wi.z*xv.z + wi.w*xv.w;
                dF[bb] += wf.x*xv.x + wf.y*xv.y + wf.z*xv.z + wf.w*xv.w;
                dG[bb] += wg.x*xv.x + wg.y*xv.y + wg.z*xv.z + wg.w*xv.w;
                dO[bb] += wo.x*xv.x + wo.y*xv.y + wo.z*xv.z + wo.w*xv.w;
            }
        }
        #pragma unroll
        for (int k4 = 0; k4 < 12; ++k4) {
            float4 wi = *reinterpret_cast<const float4*>(&Whh1[(size_t)j * PROJ + 4 * k4]);
            float4 wf = *reinterpret_cast<const float4*>(&Whh1[(size_t)(j + HID) * PROJ + 4 * k4]);
            float4 wg = *reinterpret_cast<const float4*>(&Whh1[(size_t)(j + 2 * HID) * PROJ + 4 * k4]);
            float4 wo = *reinterpret_cast<const float4*>(&Whh1[(size_t)(j + 3 * HID) * PROJ + 4 * k4]);
            #pragma unroll
            for (int bb = 0; bb < 2; ++bb) {
                float4 xv = *reinterpret_cast<const float4*>(&h1[bb][4 * k4]);
                dI[bb] += wi.x*xv.x + wi.y*xv.y + wi.z*xv.z + wi.w*xv.w;
                dF[bb] += wf.x*xv.x + wf.y*xv.y + wf.z*xv.z + wf.w*xv.w;
                dG[bb] += wg.x*xv.x + wg.y*xv.y + wg.z*xv.z + wg.w*xv.w;
                dO[bb] += wo.x*xv.x + wo.y*xv.y + wo.z*xv.z + wo.w*xv.w;
            }
        }
        #pragma unroll
        for (int bb = 0; bb < 2; ++bb) {
            float si = fsigmoid(dI[bb]), sf = fsigmoid(dF[bb]), so = fsigmoid(dO[bb]);
            float tg = ftanh(dG[bb]);
            c1[bb] = sf * c1[bb] + si * tg;
            ht[bb][j] = so * ftanh(c1[bb]);
        }
        __syncthreads();
        // ---- proj 1 -> h1/prev/PRED ----
        {
            float r0[6], r1[6];
            #pragma unroll
            for (int q = 0; q < 6; ++q) {
                int p = wave * 6 + q;
                float s0 = 0.f, s1 = 0.f;
                #pragma unroll
                for (int m = 0; m < 8; ++m) {
                    float wv = Whr1[(size_t)p * HID + lane + 64 * m];
                    s0 += wv * ht[0][lane + 64 * m];
                    s1 += wv * ht[1][lane + 64 * m];
                }
                #pragma unroll
                for (int o = 32; o; o >>= 1) { s0 += __shfl_xor(s0, o, 64); s1 += __shfl_xor(s1, o, 64); }
                r0[q] = s0; r1[q] = s1;
            }
            if (lane == 0) {
                #pragma unroll
                for (int q = 0; q < 6; ++q) {
                    int p = wave * 6 + q;
                    h1[0][p] = r0[q]; prev[0][p] = r0[q];
                    h1[1][p] = r1[q]; prev[1][p] = r1[q];
                    PRED[((size_t)t * BATCH + b0 + 0) * PROJ + p] = r0[q];
                    PRED[((size_t)t * BATCH + b0 + 1) * PROJ + p] = r1[q];
                }
            }
        }
        __syncthreads();
    }
}

// ---------------- basis contractions ----------------
__global__ void k_final(const float* __restrict__ theta, const float* __restrict__ H1,
                        const float* __restrict__ PRED, float* __restrict__ out)
{
    int b = blockIdx.x;
    __shared__ float th[2 * PROJ];
    if (threadIdx.x < 2 * PROJ) th[threadIdx.x] = theta[(size_t)b * 2 * PROJ + threadIdx.x];
    __syncthreads();
    for (int t = threadIdx.x; t < SEQ; t += 256) {
        float s = 0.f;
        #pragma unroll
        for (int p = 0; p < PROJ; ++p) s += th[PROJ + p] * H1[((size_t)t * BATCH + b) * PROJ + p];
        out[(size_t)b * SEQ + t] = s;
    }
    for (int t = threadIdx.x; t < FUT; t += 256) {
        float s = 0.f;
        #pragma unroll
        for (int p = 0; p < PROJ; ++p) s += th[p] * PRED[((size_t)t * BATCH + b) * PROJ + p];
        out[(size_t)BATCH * SEQ + (size_t)b * FUT + t] = s;
    }
}

extern "C" void kernel_launch(void* const* d_in, const int* in_sizes, int n_in,
                              void* d_out, int out_size, void* d_ws, size_t ws_size,
                              hipStream_t stream)
{
    const float* theta = (const float*)d_in[0];
    const float* xin   = (const float*)d_in[1];
    const float* xdec  = (const float*)d_in[2];
    const float* eW0i = (const float*)d_in[3];
    const float* eW0h = (const float*)d_in[4];
    const float* eb0i = (const float*)d_in[5];
    const float* eb0h = (const float*)d_in[6];
    const float* eW0r = (const float*)d_in[7];
    const float* eW1i = (const float*)d_in[8];
    const float* eW1h = (const float*)d_in[9];
    const float* eb1i = (const float*)d_in[10];
    const float* eb1h = (const float*)d_in[11];
    const float* eW1r = (const float*)d_in[12];
    const float* dW0i = (const float*)d_in[13];
    const float* dW0h = (const float*)d_in[14];
    const float* db0i = (const float*)d_in[15];
    const float* db0h = (const float*)d_in[16];
    const float* dW0r = (const float*)d_in[17];
    const float* dW1i = (const float*)d_in[18];
    const float* dW1h = (const float*)d_in[19];
    const float* db1i = (const float*)d_in[20];
    const float* db1h = (const float*)d_in[21];
    const float* dW1r = (const float*)d_in[22];

    float* ws = (float*)d_ws;
    size_t off = 0;
    float* H0   = ws + off; off += (size_t)SEQ * BATCH * PROJ;
    float* H1   = ws + off; off += (size_t)SEQ * BATCH * PROJ;
    float* PRED = ws + off; off += (size_t)FUT * BATCH * PROJ;
    float* xT   = ws + off; off += (size_t)SEQ * BATCH * INF;
    float* hs   = ws + off; off += (size_t)2 * BATCH * PROJ;
    float* cs   = ws + off; off += (size_t)2 * BATCH * HID;
    float* prev = ws + off; off += (size_t)BATCH * PROJ;
    float* Gbuf = ws + off;

    size_t availf = ws_size / sizeof(float);
    int CH = 64;
    while (CH > 1 && off + (size_t)CH * BATCH * G4 > availf) CH >>= 1;

    k_init<<<512, 256, 0, stream>>>(xin, hs, cs, prev);
    k_transpose<<<dim3(SEQ / 32, INF / 32, BATCH), dim3(32, 8), 0, stream>>>(xin, xT);

    for (int t0 = 0; t0 < SEQ; t0 += CH) {
        k_gates<<<dim3(CH, 16), 256, 0, stream>>>(xT, INF, t0 * BATCH, eW0i, eb0i, eb0h, Gbuf);
        k_rnn<<<BATCH, 512, 0, stream>>>(Gbuf, eW0h, eW0r, H0, hs, cs, t0, CH);
        k_gates<<<dim3(CH, 16), 256, 0, stream>>>(H0, PROJ, t0 * BATCH, eW1i, eb1i, eb1h, Gbuf);
        k_rnn<<<BATCH, 512, 0, stream>>>(Gbuf, eW1h, eW1r, H1, hs + BATCH * PROJ, cs + BATCH * HID, t0, CH);
    }
    k_dec<<<BATCH / 2, 512, 0, stream>>>(xdec, dW0i, dW0h, db0i, db0h, dW0r,
                                         dW1i, dW1h, db1i, db1h, dW1r,
                                         hs, cs, prev, PRED);
    k_final<<<BATCH, 256, 0, stream>>>(theta, H1, PRED, (float*)d_out);
}

// Round 2
// 10223.750 us; speedup vs baseline: 1.2171x; 1.2171x over previous
//
#include <hip/hip_runtime.h>
#include <cstdint>
#include <cstddef>

#define BATCH 128
#define INF   64
#define OUTF  16
#define SEQ   512
#define FUT   96
#define HID   512
#define G4    2048   // 4*HID
#define PROJ  48

#define NRG 16        // row(unit)-groups in decoder (32 units each)
#define NBG 8         // batch-groups in decoder (16 batches each)

__device__ __forceinline__ float fsigmoid(float x) {
    float e = __builtin_amdgcn_exp2f(-1.4426950408889634f * x);
    return __builtin_amdgcn_rcpf(1.0f + e);
}
__device__ __forceinline__ float ftanh(float x) {
    float e = __builtin_amdgcn_exp2f(2.8853900817779268f * x);
    return 1.0f - 2.0f * __builtin_amdgcn_rcpf(1.0f + e);
}

// device-coherent (cross-XCD) helpers
__device__ __forceinline__ float gload(const float* p) {
    return __hip_atomic_load(p, __ATOMIC_RELAXED, __HIP_MEMORY_SCOPE_AGENT);
}
__device__ __forceinline__ void gstore(float* p, float v) {
    __hip_atomic_store(p, v, __ATOMIC_RELAXED, __HIP_MEMORY_SCOPE_AGENT);
}
// barrier among the 16 WGs of one batch-group chain; monotonically increasing
// counter (zeroed by hipMemsetAsync each launch) -> no reset race.
__device__ __forceinline__ void gsync(unsigned* bar, unsigned target) {
    __syncthreads();
    if (threadIdx.x == 0) {
        __hip_atomic_fetch_add(bar, 1u, __ATOMIC_ACQ_REL, __HIP_MEMORY_SCOPE_AGENT);
        while (__hip_atomic_load(bar, __ATOMIC_ACQUIRE, __HIP_MEMORY_SCOPE_AGENT) < target) {
            __builtin_amdgcn_s_sleep(4);
        }
    }
    __syncthreads();
}

// ---------------- init: zero states, build first_prev ----------------
__global__ void k_init(const float* __restrict__ x, float* __restrict__ hs,
                       float* __restrict__ cs, float* __restrict__ prev) {
    int idx = blockIdx.x * 256 + threadIdx.x;
    if (idx < 2 * BATCH * PROJ) hs[idx] = 0.f;
    if (idx < 2 * BATCH * HID)  cs[idx] = 0.f;
    if (idx < BATCH * PROJ) {
        int b = idx / PROJ, p = idx % PROJ;
        prev[idx] = x[(size_t)b * INF * SEQ + (size_t)p * SEQ + (SEQ - 1)];
    }
}

// ---------------- transpose x[b][k][t] -> xT[(t*B+b)*INF + k] ----------------
__global__ void k_transpose(const float* __restrict__ x, float* __restrict__ xT) {
    __shared__ float tile[32][33];
    int b  = blockIdx.z;
    int t0 = blockIdx.x * 32;
    int k0 = blockIdx.y * 32;
    int tx = threadIdx.x, ty = threadIdx.y; // 32 x 8
    #pragma unroll
    for (int i = 0; i < 4; ++i) {
        int k = k0 + ty + 8 * i;
        tile[ty + 8 * i][tx] = x[(size_t)b * INF * SEQ + (size_t)k * SEQ + t0 + tx];
    }
    __syncthreads();
    #pragma unroll
    for (int i = 0; i < 4; ++i) {
        int t = t0 + ty + 8 * i;
        xT[((size_t)t * BATCH + b) * INF + k0 + tx] = tile[tx][ty + 8 * i];
    }
}

// ---------------- input-gates GEMM ----------------
__global__ __launch_bounds__(256) void k_gates(
    const float* __restrict__ A, int K, int row0,
    const float* __restrict__ W, const float* __restrict__ bih,
    const float* __restrict__ bhh, float* __restrict__ G)
{
    __shared__ float Ast[16][132];
    __shared__ float Wst[16][132];
    int rb = blockIdx.x * 128;
    int cb = blockIdx.y * 128;
    int tid = threadIdx.x;
    int rg = tid & 15;
    int cg = tid >> 4;
    float acc[8][8];
    #pragma unroll
    for (int j = 0; j < 8; ++j)
        #pragma unroll
        for (int i = 0; i < 8; ++i) acc[j][i] = 0.f;

    int nk = K / 16;
    for (int ko = 0; ko < nk; ++ko) {
        #pragma unroll
        for (int l = 0; l < 8; ++l) {
            int idx = tid + l * 256;
            int r = idx >> 4, k = idx & 15;
            Ast[k][r] = A[(size_t)(row0 + rb + r) * K + ko * 16 + k];
            Wst[k][r] = W[(size_t)(cb + r) * K + ko * 16 + k];
        }
        __syncthreads();
        #pragma unroll
        for (int k = 0; k < 16; ++k) {
            float4 a0 = *reinterpret_cast<const float4*>(&Ast[k][rg * 8]);
            float4 a1 = *reinterpret_cast<const float4*>(&Ast[k][rg * 8 + 4]);
            float4 w0 = *reinterpret_cast<const float4*>(&Wst[k][cg * 8]);
            float4 w1 = *reinterpret_cast<const float4*>(&Wst[k][cg * 8 + 4]);
            float av[8] = {a0.x, a0.y, a0.z, a0.w, a1.x, a1.y, a1.z, a1.w};
            float wv[8] = {w0.x, w0.y, w0.z, w0.w, w1.x, w1.y, w1.z, w1.w};
            #pragma unroll
            for (int j = 0; j < 8; ++j)
                #pragma unroll
                for (int i = 0; i < 8; ++i) acc[j][i] += av[j] * wv[i];
        }
        __syncthreads();
    }
    int c0 = cb + cg * 8;
    float bsum[8];
    #pragma unroll
    for (int i = 0; i < 8; ++i) bsum[i] = bih[c0 + i] + bhh[c0 + i];
    #pragma unroll
    for (int j = 0; j < 8; ++j) {
        int r = rb + rg * 8 + j;
        float4 o0, o1;
        o0.x = acc[j][0] + bsum[0]; o0.y = acc[j][1] + bsum[1];
        o0.z = acc[j][2] + bsum[2]; o0.w = acc[j][3] + bsum[3];
        o1.x = acc[j][4] + bsum[4]; o1.y = acc[j][5] + bsum[5];
        o1.z = acc[j][6] + bsum[6]; o1.w = acc[j][7] + bsum[7];
        *reinterpret_cast<float4*>(&G[(size_t)r * G4 + c0])     = o0;
        *reinterpret_cast<float4*>(&G[(size_t)r * G4 + c0 + 4]) = o1;
    }
}

// ---------------- encoder recurrent phase: one WG per batch element ----------------
__global__ __launch_bounds__(512) void k_rnn(
    const float* __restrict__ G,
    const float* __restrict__ Whh,
    const float* __restrict__ Whr,
    float* __restrict__ Hout,
    float* __restrict__ h_state,
    float* __restrict__ c_state,
    int t0, int nt)
{
    __shared__ float whr_lo[PROJ][256];
    __shared__ __align__(16) float ht_lds[HID];
    __shared__ __align__(16) float h_cur[PROJ];
    int b = blockIdx.x;
    int j = threadIdx.x;
    int wave = j >> 6, lane = j & 63;

    float wI[PROJ], wF[PROJ], wG[PROJ], wO[PROJ];
    #pragma unroll
    for (int k4 = 0; k4 < 12; ++k4) {
        float4 vi = *reinterpret_cast<const float4*>(&Whh[(size_t)j * PROJ + 4 * k4]);
        float4 vf = *reinterpret_cast<const float4*>(&Whh[(size_t)(j + HID) * PROJ + 4 * k4]);
        float4 vg = *reinterpret_cast<const float4*>(&Whh[(size_t)(j + 2 * HID) * PROJ + 4 * k4]);
        float4 vo = *reinterpret_cast<const float4*>(&Whh[(size_t)(j + 3 * HID) * PROJ + 4 * k4]);
        wI[4*k4+0]=vi.x; wI[4*k4+1]=vi.y; wI[4*k4+2]=vi.z; wI[4*k4+3]=vi.w;
        wF[4*k4+0]=vf.x; wF[4*k4+1]=vf.y; wF[4*k4+2]=vf.z; wF[4*k4+3]=vf.w;
        wG[4*k4+0]=vg.x; wG[4*k4+1]=vg.y; wG[4*k4+2]=vg.z; wG[4*k4+3]=vg.w;
        wO[4*k4+0]=vo.x; wO[4*k4+1]=vo.y; wO[4*k4+2]=vo.z; wO[4*k4+3]=vo.w;
    }
    for (int idx = j; idx < PROJ * 256; idx += 512) {
        int p = idx >> 8, jj = idx & 255;
        whr_lo[p][jj] = Whr[(size_t)p * HID + jj];
    }
    float wr[6][4];
    #pragma unroll
    for (int q = 0; q < 6; ++q)
        #pragma unroll
        for (int m = 0; m < 4; ++m)
            wr[q][m] = Whr[(size_t)(wave * 6 + q) * HID + 256 + lane + 64 * m];

    float c = c_state[(size_t)b * HID + j];
    if (j < PROJ) h_cur[j] = h_state[(size_t)b * PROJ + j];
    __syncthreads();

    const float* Gr = G + (size_t)b * G4;
    float gi = Gr[j], gf = Gr[j + HID], gg = Gr[j + 2 * HID], go = Gr[j + 3 * HID];

    for (int ct = 0; ct < nt; ++ct) {
        float ai = gi, af = gf, ag = gg, ao = go;
        #pragma unroll
        for (int k4 = 0; k4 < 12; ++k4) {
            float4 h4 = *reinterpret_cast<const float4*>(&h_cur[4 * k4]);
            ai += wI[4*k4+0]*h4.x + wI[4*k4+1]*h4.y + wI[4*k4+2]*h4.z + wI[4*k4+3]*h4.w;
            af += wF[4*k4+0]*h4.x + wF[4*k4+1]*h4.y + wF[4*k4+2]*h4.z + wF[4*k4+3]*h4.w;
            ag += wG[4*k4+0]*h4.x + wG[4*k4+1]*h4.y + wG[4*k4+2]*h4.z + wG[4*k4+3]*h4.w;
            ao += wO[4*k4+0]*h4.x + wO[4*k4+1]*h4.y + wO[4*k4+2]*h4.z + wO[4*k4+3]*h4.w;
        }
        if (ct + 1 < nt) {
            const float* Gn = G + ((size_t)(ct + 1) * BATCH + b) * G4;
            gi = Gn[j]; gf = Gn[j + HID]; gg = Gn[j + 2 * HID]; go = Gn[j + 3 * HID];
        }
        float si = fsigmoid(ai), sf = fsigmoid(af), so = fsigmoid(ao), tg = ftanh(ag);
        c = sf * c + si * tg;
        ht_lds[j] = so * ftanh(c);
        __syncthreads();
        float rq[6];
        #pragma unroll
        for (int q = 0; q < 6; ++q) {
            int p = wave * 6 + q;
            float s = 0.f;
            #pragma unroll
            for (int m = 0; m < 4; ++m) s += whr_lo[p][lane + 64 * m] * ht_lds[lane + 64 * m];
            #pragma unroll
            for (int m = 0; m < 4; ++m) s += wr[q][m] * ht_lds[256 + lane + 64 * m];
            #pragma unroll
            for (int o = 32; o; o >>= 1) s += __shfl_xor(s, o, 64);
            rq[q] = s;
        }
        if (lane == 0) {
            int t = t0 + ct;
            #pragma unroll
            for (int q = 0; q < 6; ++q) {
                h_cur[wave * 6 + q] = rq[q];
                Hout[((size_t)t * BATCH + b) * PROJ + wave * 6 + q] = rq[q];
            }
        }
        __syncthreads();
    }
    c_state[(size_t)b * HID + j] = c;
    if (j < PROJ) h_state[(size_t)b * PROJ + j] = h_cur[j];
}

// ---------------- decoder: weights-stationary cooperative kernel ----------------
// 128 WGs = 16 unit-groups (rg: 32 units, weights in VGPRs) x 8 batch-groups
// (bg: 16 batches). Each bg's 16 WGs form an independent barrier chain.
// Lane mapping (gates): l = kq*16 + (g*4 + ui); wave w covers units w*4+ui.
// Each lane accumulates a k-quarter partial for all 16 batches; butterfly over
// kq (xor 16,32); kq==0 lanes deposit to xch; (u,b) threads do c-update.
__global__ __launch_bounds__(512) void k_dec_coop(
    const float* __restrict__ xdec,
    const float* __restrict__ Wih0, const float* __restrict__ Whh0,
    const float* __restrict__ bih0, const float* __restrict__ bhh0,
    const float* __restrict__ Whr0,
    const float* __restrict__ Wih1, const float* __restrict__ Whh1,
    const float* __restrict__ bih1, const float* __restrict__ bhh1,
    const float* __restrict__ Whr1,
    const float* __restrict__ hs,    // [2][B][48] encoder final h
    const float* __restrict__ cs,    // [2][B][512] encoder final c
    const float* __restrict__ prev0, // [B][48] first_prev
    float* __restrict__ ht0g,        // [B][512]
    float* __restrict__ ht1g,        // [B][512]
    float* __restrict__ h0g,         // [B][48]
    float* __restrict__ h1g,         // [B][48]
    float* __restrict__ PRED,        // [FUT][B][48]
    unsigned* __restrict__ bar)      // [NBG][32]
{
    const int wg = blockIdx.x;
    const int rg = wg & (NRG - 1);
    const int bg = wg >> 4;
    const int tid = threadIdx.x;
    const int w = tid >> 6, l = tid & 63;
    const int kq = l >> 4, gu = l & 15, g = gu >> 2, ui = gu & 3;
    const int u_w  = w * 4 + ui;          // unit-within-rg for this lane's rows
    const int gr0  = g * 512 + rg * 32 + u_w;  // gate-row (same for L0/L1)
    // c-update mapping
    const int cu = tid >> 4;              // unit-within-rg 0..31
    const int cb = tid & 15;              // batch-within-bg 0..15
    const int bglob = bg * 16 + cb;
    const int uglob = rg * 32 + cu;

    __shared__ __align__(16) float inp0[16][112];
    __shared__ __align__(16) float inp1[16][96];
    __shared__ __align__(16) float xch[4 * 512];

    // ---- one-time weight preload into VGPRs ----
    float W0v[28], W1v[24], Wr0v[24], Wr1v[24];
    #pragma unroll
    for (int kk = 0; kk < 28; ++kk) {
        int k = kq * 28 + kk;
        W0v[kk] = (k < 48) ? Whh0[(size_t)gr0 * 48 + k]
                           : Wih0[(size_t)gr0 * 64 + (k - 48)];
    }
    #pragma unroll
    for (int kk = 0; kk < 24; ++kk) {
        int k = kq * 24 + kk;
        W1v[kk] = (k < 48) ? Whh1[(size_t)gr0 * 48 + k]
                           : Wih1[(size_t)gr0 * 48 + (k - 48)];
    }
    #pragma unroll
    for (int pp = 0; pp < 3; ++pp)
        #pragma unroll
        for (int m = 0; m < 8; ++m) {
            Wr0v[pp * 8 + m] = Whr0[(size_t)(3 * rg + pp) * 512 + l + 64 * m];
            Wr1v[pp * 8 + m] = Whr1[(size_t)(3 * rg + pp) * 512 + l + 64 * m];
        }
    // biases + c for (cu,cb) threads
    float bs0[4], bs1[4];
    #pragma unroll
    for (int gg2 = 0; gg2 < 4; ++gg2) {
        int r = gg2 * 512 + uglob;
        bs0[gg2] = bih0[r] + bhh0[r];
        bs1[gg2] = bih1[r] + bhh1[r];
    }
    float c0 = cs[(size_t)bglob * 512 + uglob];
    float c1 = cs[(size_t)(BATCH + bglob) * 512 + uglob];

    unsigned* mybar = bar + bg * 32;
    unsigned scount = 0;

    for (int t = 0; t < FUT; ++t) {
        const float* h0src = t ? h0g : hs;
        const float* h1src = t ? h1g : (hs + BATCH * PROJ);
        const float* prevsrc = t ? h1g : prev0;

        // ---- stage inp0 = [h0(48), prev(48), x_t(16)] ----
        for (int i = tid; i < 16 * 112; i += 512) {
            int b = i / 112, k = i % 112;
            float v;
            if (k < 48)      v = gload(&h0src[(size_t)(bg * 16 + b) * PROJ + k]);
            else if (k < 96) v = gload(&prevsrc[(size_t)(bg * 16 + b) * PROJ + (k - 48)]);
            else             v = xdec[(size_t)(bg * 16 + b) * OUTF * FUT + (size_t)(k - 96) * FUT + t];
            inp0[b][k] = v;
        }
        __syncthreads();

        // ---- L0 gate partials (k-quarter per lane, all 16 batches) ----
        {
            float acc[16];
            #pragma unroll
            for (int b = 0; b < 16; ++b) acc[b] = 0.f;
            #pragma unroll
            for (int k4 = 0; k4 < 7; ++k4) {
                #pragma unroll
                for (int b = 0; b < 16; ++b) {
                    float4 v = *reinterpret_cast<const float4*>(&inp0[b][kq * 28 + k4 * 4]);
                    acc[b] += W0v[k4*4+0]*v.x + W0v[k4*4+1]*v.y + W0v[k4*4+2]*v.z + W0v[k4*4+3]*v.w;
                }
            }
            #pragma unroll
            for (int b = 0; b < 16; ++b) {
                float v = acc[b];
                v += __shfl_xor(v, 16);
                v += __shfl_xor(v, 32);
                acc[b] = v;
            }
            if (kq == 0) {
                int base = g * 512 + u_w * 16;
                #pragma unroll
                for (int q = 0; q < 4; ++q) {
                    float4 f;
                    f.x = acc[q*4+0]; f.y = acc[q*4+1]; f.z = acc[q*4+2]; f.w = acc[q*4+3];
                    *reinterpret_cast<float4*>(&xch[base + 4 * q]) = f;
                }
            }
        }
        __syncthreads();
        // ---- c0 update + ht0 ----
        {
            float gi = xch[0    + cu * 16 + cb] + bs0[0];
            float gf = xch[512  + cu * 16 + cb] + bs0[1];
            float gc = xch[1024 + cu * 16 + cb] + bs0[2];
            float go = xch[1536 + cu * 16 + cb] + bs0[3];
            float si = fsigmoid(gi), sf = fsigmoid(gf), so = fsigmoid(go), tg = ftanh(gc);
            c0 = sf * c0 + si * tg;
            gstore(&ht0g[(size_t)bglob * 512 + uglob], so * ftanh(c0));
        }
        gsync(mybar, (++scount) * NRG);   // sync 1: ht0 complete

        // ---- proj0: wave w -> batches 2w,2w+1; rg -> p = 3rg..3rg+2 ----
        {
            #pragma unroll
            for (int bb = 0; bb < 2; ++bb) {
                int b = 2 * w + bb;
                float hv[8];
                #pragma unroll
                for (int m = 0; m < 8; ++m)
                    hv[m] = gload(&ht0g[(size_t)(bg * 16 + b) * 512 + l + 64 * m]);
                #pragma unroll
                for (int pp = 0; pp < 3; ++pp) {
                    float s = 0.f;
                    #pragma unroll
                    for (int m = 0; m < 8; ++m) s += Wr0v[pp * 8 + m] * hv[m];
                    #pragma unroll
                    for (int o = 32; o; o >>= 1) s += __shfl_xor(s, o, 64);
                    if (l == 0)
                        gstore(&h0g[(size_t)(bg * 16 + b) * PROJ + 3 * rg + pp], s);
                }
            }
        }
        gsync(mybar, (++scount) * NRG);   // sync 2: h0' complete

        // ---- stage inp1 = [h1(48), h0'(48)] ----
        for (int i = tid; i < 16 * 96; i += 512) {
            int b = i / 96, k = i % 96;
            float v = (k < 48) ? gload(&h1src[(size_t)(bg * 16 + b) * PROJ + k])
                               : gload(&h0g[(size_t)(bg * 16 + b) * PROJ + (k - 48)]);
            inp1[b][k] = v;
        }
        __syncthreads();

        // ---- L1 gate partials ----
        {
            float acc[16];
            #pragma unroll
            for (int b = 0; b < 16; ++b) acc[b] = 0.f;
            #pragma unroll
            for (int k4 = 0; k4 < 6; ++k4) {
                #pragma unroll
                for (int b = 0; b < 16; ++b) {
                    float4 v = *reinterpret_cast<const float4*>(&inp1[b][kq * 24 + k4 * 4]);
                    acc[b] += W1v[k4*4+0]*v.x + W1v[k4*4+1]*v.y + W1v[k4*4+2]*v.z + W1v[k4*4+3]*v.w;
                }
            }
            #pragma unroll
            for (int b = 0; b < 16; ++b) {
                float v = acc[b];
                v += __shfl_xor(v, 16);
                v += __shfl_xor(v, 32);
                acc[b] = v;
            }
            if (kq == 0) {
                int base = g * 512 + u_w * 16;
                #pragma unroll
                for (int q = 0; q < 4; ++q) {
                    float4 f;
                    f.x = acc[q*4+0]; f.y = acc[q*4+1]; f.z = acc[q*4+2]; f.w = acc[q*4+3];
                    *reinterpret_cast<float4*>(&xch[base + 4 * q]) = f;
                }
            }
        }
        __syncthreads();
        // ---- c1 update + ht1 ----
        {
            float gi = xch[0    + cu * 16 + cb] + bs1[0];
            float gf = xch[512  + cu * 16 + cb] + bs1[1];
            float gc = xch[1024 + cu * 16 + cb] + bs1[2];
            float go = xch[1536 + cu * 16 + cb] + bs1[3];
            float si = fsigmoid(gi), sf = fsigmoid(gf), so = fsigmoid(go), tg = ftanh(gc);
            c1 = sf * c1 + si * tg;
            gstore(&ht1g[(size_t)bglob * 512 + uglob], so * ftanh(c1));
        }
        gsync(mybar, (++scount) * NRG);   // sync 3: ht1 complete

        // ---- proj1 -> h1g (=prev) + PRED ----
        {
            #pragma unroll
            for (int bb = 0; bb < 2; ++bb) {
                int b = 2 * w + bb;
                float hv[8];
                #pragma unroll
                for (int m = 0; m < 8; ++m)
                    hv[m] = gload(&ht1g[(size_t)(bg * 16 + b) * 512 + l + 64 * m]);
                #pragma unroll
                for (int pp = 0; pp < 3; ++pp) {
                    float s = 0.f;
                    #pragma unroll
                    for (int m = 0; m < 8; ++m) s += Wr1v[pp * 8 + m] * hv[m];
                    #pragma unroll
                    for (int o = 32; o; o >>= 1) s += __shfl_xor(s, o, 64);
                    if (l == 0) {
                        gstore(&h1g[(size_t)(bg * 16 + b) * PROJ + 3 * rg + pp], s);
                        gstore(&PRED[((size_t)t * BATCH + bg * 16 + b) * PROJ + 3 * rg + pp], s);
                    }
                }
            }
        }
        gsync(mybar, (++scount) * NRG);   // sync 4: h1'/prev complete
    }
}

// ---------------- basis contractions ----------------
__global__ void k_final(const float* __restrict__ theta, const float* __restrict__ H1,
                        const float* __restrict__ PRED, float* __restrict__ out)
{
    int b = blockIdx.x;
    __shared__ float th[2 * PROJ];
    if (threadIdx.x < 2 * PROJ) th[threadIdx.x] = theta[(size_t)b * 2 * PROJ + threadIdx.x];
    __syncthreads();
    for (int t = threadIdx.x; t < SEQ; t += 256) {
        float s = 0.f;
        #pragma unroll
        for (int p = 0; p < PROJ; ++p) s += th[PROJ + p] * H1[((size_t)t * BATCH + b) * PROJ + p];
        out[(size_t)b * SEQ + t] = s;
    }
    for (int t = threadIdx.x; t < FUT; t += 256) {
        float s = 0.f;
        #pragma unroll
        for (int p = 0; p < PROJ; ++p) s += th[p] * PRED[((size_t)t * BATCH + b) * PROJ + p];
        out[(size_t)BATCH * SEQ + (size_t)b * FUT + t] = s;
    }
}

extern "C" void kernel_launch(void* const* d_in, const int* in_sizes, int n_in,
                              void* d_out, int out_size, void* d_ws, size_t ws_size,
                              hipStream_t stream)
{
    (void)in_sizes; (void)n_in; (void)out_size;
    const float* theta = (const float*)d_in[0];
    const float* xin   = (const float*)d_in[1];
    const float* xdec  = (const float*)d_in[2];
    const float* eW0i = (const float*)d_in[3];
    const float* eW0h = (const float*)d_in[4];
    const float* eb0i = (const float*)d_in[5];
    const float* eb0h = (const float*)d_in[6];
    const float* eW0r = (const float*)d_in[7];
    const float* eW1i = (const float*)d_in[8];
    const float* eW1h = (const float*)d_in[9];
    const float* eb1i = (const float*)d_in[10];
    const float* eb1h = (const float*)d_in[11];
    const float* eW1r = (const float*)d_in[12];
    const float* dW0i = (const float*)d_in[13];
    const float* dW0h = (const float*)d_in[14];
    const float* db0i = (const float*)d_in[15];
    const float* db0h = (const float*)d_in[16];
    const float* dW0r = (const float*)d_in[17];
    const float* dW1i = (const float*)d_in[18];
    const float* dW1h = (const float*)d_in[19];
    const float* db1i = (const float*)d_in[20];
    const float* db1h = (const float*)d_in[21];
    const float* dW1r = (const float*)d_in[22];

    float* ws = (float*)d_ws;
    size_t off = 0;
    float* H0   = ws + off; off += (size_t)SEQ * BATCH * PROJ;
    float* H1   = ws + off; off += (size_t)SEQ * BATCH * PROJ;
    float* PRED = ws + off; off += (size_t)FUT * BATCH * PROJ;
    float* xT   = ws + off; off += (size_t)SEQ * BATCH * INF;
    float* hs   = ws + off; off += (size_t)2 * BATCH * PROJ;
    float* cs   = ws + off; off += (size_t)2 * BATCH * HID;
    float* prev = ws + off; off += (size_t)BATCH * PROJ;
    float* ht0g = ws + off; off += (size_t)BATCH * HID;
    float* ht1g = ws + off; off += (size_t)BATCH * HID;
    float* h0g  = ws + off; off += (size_t)BATCH * PROJ;
    float* h1g  = ws + off; off += (size_t)BATCH * PROJ;
    off = (off + 63) & ~(size_t)63;
    unsigned* bar = (unsigned*)(ws + off); off += NBG * 32;
    float* Gbuf = ws + off;

    size_t availf = ws_size / sizeof(float);
    int CH = 64;
    while (CH > 1 && off + (size_t)CH * BATCH * G4 > availf) CH >>= 1;

    k_init<<<512, 256, 0, stream>>>(xin, hs, cs, prev);
    k_transpose<<<dim3(SEQ / 32, INF / 32, BATCH), dim3(32, 8), 0, stream>>>(xin, xT);

    for (int t0 = 0; t0 < SEQ; t0 += CH) {
        k_gates<<<dim3(CH, 16), 256, 0, stream>>>(xT, INF, t0 * BATCH, eW0i, eb0i, eb0h, Gbuf);
        k_rnn<<<BATCH, 512, 0, stream>>>(Gbuf, eW0h, eW0r, H0, hs, cs, t0, CH);
        k_gates<<<dim3(CH, 16), 256, 0, stream>>>(H0, PROJ, t0 * BATCH, eW1i, eb1i, eb1h, Gbuf);
        k_rnn<<<BATCH, 512, 0, stream>>>(Gbuf, eW1h, eW1r, H1, hs + BATCH * PROJ, cs + BATCH * HID, t0, CH);
    }

    hipMemsetAsync(bar, 0, NBG * 32 * sizeof(unsigned), stream);
    k_dec_coop<<<NRG * NBG, 512, 0, stream>>>(xdec, dW0i, dW0h, db0i, db0h, dW0r,
                                              dW1i, dW1h, db1i, db1h, dW1r,
                                              hs, cs, prev, ht0g, ht1g, h0g, h1g, PRED, bar);
    k_final<<<BATCH, 256, 0, stream>>>(theta, H1, PRED, (float*)d_out);
}